// Round 6
// baseline (2702.310 us; speedup 1.0000x reference)
//
#include <hip/hip_runtime.h>
#include <hip/hip_bf16.h>

typedef unsigned int uint;
typedef unsigned short ushort;

typedef __bf16 bf16x8 __attribute__((ext_vector_type(8)));
typedef float f32x16 __attribute__((ext_vector_type(16)));

#define ITX   62                 // input tile width (32 + 31 - 1)
#define ROWB  (ITX * 32)         // 1984 B per LDS row (62 px * 16ch * 2B)
#define LROWS 63                 // rows 0..62 staged (max consumed = wv*4+34 = 62)
#define LDS_BYTES (LROWS * ROWB) // 124992 < 160K

#define MFMA32(a, b, c) __builtin_amdgcn_mfma_f32_32x32x16_bf16((a), (b), (c), 0, 0, 0)

__device__ __forceinline__ ushort f2bf(float f) {
  uint x = __builtin_bit_cast(uint, f);
  x += 0x7fffu + ((x >> 16) & 1u);   // round-to-nearest-even
  return (ushort)(x >> 16);
}

// ---------------- pre-pass 1: NCHW fp32 -> NHWC bf16 (unchanged) ----------------
extern "C" __global__ void cvt_sig(const float* __restrict__ in, ushort* __restrict__ out) {
  uint chunk = blockIdx.x * 256 + threadIdx.x;     // 16*256*256*4 = 4194304 total
  uint g = chunk & 3u;
  uint x = (chunk >> 2) & 255u;
  uint y = (chunk >> 10) & 255u;
  uint b = chunk >> 18;
  const float* src = in + (((size_t)b * 32 + g * 8) * 256 + y) * 256 + x;
  uint w0 = (uint)f2bf(src[0])         | ((uint)f2bf(src[1 * 65536]) << 16);
  uint w1 = (uint)f2bf(src[2 * 65536]) | ((uint)f2bf(src[3 * 65536]) << 16);
  uint w2 = (uint)f2bf(src[4 * 65536]) | ((uint)f2bf(src[5 * 65536]) << 16);
  uint w3 = (uint)f2bf(src[6 * 65536]) | ((uint)f2bf(src[7 * 65536]) << 16);
  *(uint4*)(out + (size_t)chunk * 8) = make_uint4(w0, w1, w2, w3);
}

// ---------------- pre-pass 2: weights -> bf16, layout wt[h][kx][ky(32, pad0)][frag] ----
// flat ushort idx = (((h*31+kx)*32 + ky)*64 + j)*8 + i ; j: col=j&31 (cout), g=j>>5
// element i: c = h*16 + g*8 + i ; ky==31 is a zero pad line.
extern "C" __global__ void cvt_wt(const float* __restrict__ w, ushort* __restrict__ wt) {
  uint tid = blockIdx.x * 256 + threadIdx.x;       // 2*31*32*512 = 1015808 total
  uint i = tid & 7u;
  uint j = (tid >> 3) & 63u;
  uint rest = tid >> 9;                            // < 1984
  uint ky = rest & 31u;
  uint kxh = rest >> 5;                            // < 62
  uint kx = kxh % 31u;
  uint h  = kxh / 31u;
  uint col = j & 31u;
  uint g   = j >> 5;
  uint c = h * 16u + g * 8u + i;
  float v = 0.0f;
  if (ky < 31u) v = w[((col * 32u + c) * 31u + ky) * 31u + kx];
  wt[tid] = f2bf(v);
}

// ---------------- main conv: 32x32 tile, 8 waves, kx-outer / ky-inner ----------------
// A ring depth 8 (ds_read 5 phases ahead), B ring depth 4 (global 4 phases ahead).
// PHASE(kk): MFMA rows kk..kk+3 (ring slots kk..kk+3 mod 8) x B line kk; then
// prefetch B line kk+4 and A row kk+8.
#define PHASE(qa, qb, qc, qd, breg, kk)                                        \
  acc0 = MFMA32(qa, breg, acc0);                                               \
  acc1 = MFMA32(qb, breg, acc1);                                               \
  acc2 = MFMA32(qc, breg, acc2);                                               \
  acc3 = MFMA32(qd, breg, acc3);                                               \
  if ((kk) + 4 < 32) breg = *(const bf16x8*)(wb + ((kk) + 4) * 1024 + lane * 16); \
  if ((kk) + 8 <= 34) qa = *(const bf16x8*)(ab + ((kk) + 8) * ROWB);

#define GROUP8(k0)                         \
  PHASE(q0, q1, q2, q3, bA, (k0) + 0)      \
  PHASE(q1, q2, q3, q4, bB, (k0) + 1)      \
  PHASE(q2, q3, q4, q5, bC, (k0) + 2)      \
  PHASE(q3, q4, q5, q6, bD, (k0) + 3)      \
  PHASE(q4, q5, q6, q7, bA, (k0) + 4)      \
  PHASE(q5, q6, q7, q0, bB, (k0) + 5)      \
  PHASE(q6, q7, q0, q1, bC, (k0) + 6)      \
  PHASE(q7, q0, q1, q2, bD, (k0) + 7)

extern "C" __global__ void __launch_bounds__(512, 2)
conv_main(const ushort* __restrict__ sigbf, const char* __restrict__ wtbf,
          const float* __restrict__ bias, float* __restrict__ out) {
  extern __shared__ char lds[];
  const int tid = threadIdx.x;
  const int lane = tid & 63;
  const int wv  = tid >> 6;        // 0..7, owns output rows wv*4 .. wv*4+3
  const int l31 = lane & 31;       // = M row (ox offset) for A, = cout col for B/C
  const int hi  = lane >> 5;       // k-half selector of the fragment
  const int ox0 = blockIdx.x * 32, oy0 = blockIdx.y * 32;
  const int bb = blockIdx.z;

  f32x16 acc0, acc1, acc2, acc3;
#pragma unroll
  for (int i = 0; i < 16; ++i) { acc0[i] = 0.f; acc1[i] = 0.f; acc2[i] = 0.f; acc3[i] = 0.f; }

  for (int h = 0; h < 2; ++h) {     // two 16-channel halves; acc persists
    if (h) __syncthreads();         // previous half's compute done before overwrite
    // ---- stage input tile half: 63*62 pixels * 16ch bf16, linear 16B chunks ----
#pragma unroll
    for (int it = 0; it < 16; ++it) {
      int c = it * 512 + tid;
      if (c < 63 * 62 * 2) {
        int p = c >> 1, sub = c & 1;
        int ty = p / ITX;
        int tx = p - ty * ITX;
        int gy = oy0 + ty; gy = gy > 255 ? 255 : gy;   // clamp: only feeds discarded outputs
        int gx = ox0 + tx; gx = gx > 255 ? 255 : gx;
        uint4 v = *(const uint4*)(sigbf +
            ((((size_t)bb << 8) + gy) * 256 + gx) * 32 + h * 16 + sub * 8);
        *(uint4*)(lds + (uint)(ty * ROWB + tx * 32 + sub * 16)) = v;
      }
    }
    __syncthreads();

    const char* wcol = wtbf + (((size_t)h * 31) << 15);
#pragma unroll 1
    for (int kx = 0; kx < 31; ++kx) {
      const char* wb = wcol + ((size_t)kx << 15);      // 32KB contiguous ky-column
      int col = l31 + kx;                              // 0..61 (real cols consumed <= 61)
      const char* ab = lds + (uint)(wv * 4) * ROWB + (uint)col * 32u + (uint)hi * 16u;
      // A ring init: rows wv*4 + 0..7 (slot = relative row mod 8)
      bf16x8 q0 = *(const bf16x8*)(ab + 0 * ROWB);
      bf16x8 q1 = *(const bf16x8*)(ab + 1 * ROWB);
      bf16x8 q2 = *(const bf16x8*)(ab + 2 * ROWB);
      bf16x8 q3 = *(const bf16x8*)(ab + 3 * ROWB);
      bf16x8 q4 = *(const bf16x8*)(ab + 4 * ROWB);
      bf16x8 q5 = *(const bf16x8*)(ab + 5 * ROWB);
      bf16x8 q6 = *(const bf16x8*)(ab + 6 * ROWB);
      bf16x8 q7 = *(const bf16x8*)(ab + 7 * ROWB);
      // B ring init: lines 0..3
      bf16x8 bA = *(const bf16x8*)(wb + 0 * 1024 + lane * 16);
      bf16x8 bB = *(const bf16x8*)(wb + 1 * 1024 + lane * 16);
      bf16x8 bC = *(const bf16x8*)(wb + 2 * 1024 + lane * 16);
      bf16x8 bD = *(const bf16x8*)(wb + 3 * 1024 + lane * 16);
      GROUP8(0)
      GROUP8(8)
      GROUP8(16)
      GROUP8(24)     // taps 24..31; tap 31 is the zero pad line
    }
  }

  // ---- epilogue: C/D layout col=lane&31 (=cout), row=(r&3)+8*(r>>2)+4*hi (=ox) ----
  float bv = bias[l31];
  f32x16 accv[4] = {acc0, acc1, acc2, acc3};
#pragma unroll
  for (int t = 0; t < 4; ++t) {
    int oy = oy0 + wv * 4 + t;
    if (oy >= 226) continue;
    size_t ob = (((size_t)bb * 32 + l31) * 226 + oy) * 226;
#pragma unroll
    for (int q = 0; q < 4; ++q) {
      int ox = ox0 + q * 8 + hi * 4;
      float4 v = make_float4(accv[t][4 * q + 0] + bv, accv[t][4 * q + 1] + bv,
                             accv[t][4 * q + 2] + bv, accv[t][4 * q + 3] + bv);
      if (ox + 3 < 226) {
        *(float4*)(out + ob + ox) = v;
      } else {
        if (ox + 0 < 226) out[ob + ox + 0] = v.x;
        if (ox + 1 < 226) out[ob + ox + 1] = v.y;
        if (ox + 2 < 226) out[ob + ox + 2] = v.z;
        if (ox + 3 < 226) out[ob + ox + 3] = v.w;
      }
    }
  }
}

extern "C" void kernel_launch(void* const* d_in, const int* in_sizes, int n_in,
                              void* d_out, int out_size, void* d_ws, size_t ws_size,
                              hipStream_t stream) {
  const float* sig = (const float*)d_in[0];
  const float* wgt = (const float*)d_in[1];
  const float* bia = (const float*)d_in[2];
  float* out = (float*)d_out;
  ushort* sigbf = (ushort*)d_ws;                       // 16*256*256*32 bf16 = 64 MiB
  char*   wtbf  = (char*)d_ws + 67108864;              // 2*31*32KB = 1.94 MiB

  (void)hipFuncSetAttribute(reinterpret_cast<const void*>(conv_main),
                            hipFuncAttributeMaxDynamicSharedMemorySize, LDS_BYTES);

  cvt_sig<<<16384, 256, 0, stream>>>(sig, sigbf);
  cvt_wt<<<3968, 256, 0, stream>>>(wgt, (ushort*)wtbf);
  conv_main<<<dim3(8, 8, 16), 512, LDS_BYTES, stream>>>(sigbf, wtbf, bia, out);

  (void)in_sizes; (void)n_in; (void)out_size; (void)ws_size;
}

// Round 7
// 1791.630 us; speedup vs baseline: 1.5083x; 1.5083x over previous
//
#include <hip/hip_runtime.h>
#include <hip/hip_bf16.h>

typedef unsigned int uint;
typedef unsigned short ushort;

typedef __bf16 bf16x8 __attribute__((ext_vector_type(8)));
typedef float f32x16 __attribute__((ext_vector_type(16)));

#define ITX   62                 // input tile width (32 + 31 - 1)
#define ROWB  (ITX * 32)         // 1984 B per LDS row (62 px * 16ch * 2B)
#define LROWS 64                 // 63 staged rows + 1 ring-spill row
#define LDS_BYTES (LROWS * ROWB) // 126976 < 160K

#define MFMA32(a, b, c) __builtin_amdgcn_mfma_f32_32x32x16_bf16((a), (b), (c), 0, 0, 0)

__device__ __forceinline__ ushort f2bf(float f) {
  uint x = __builtin_bit_cast(uint, f);
  x += 0x7fffu + ((x >> 16) & 1u);   // round-to-nearest-even
  return (ushort)(x >> 16);
}

// ---------------- pre-pass 1: NCHW fp32 -> NHWC bf16 (unchanged) ----------------
extern "C" __global__ void cvt_sig(const float* __restrict__ in, ushort* __restrict__ out) {
  uint chunk = blockIdx.x * 256 + threadIdx.x;     // 16*256*256*4 = 4194304 total
  uint g = chunk & 3u;
  uint x = (chunk >> 2) & 255u;
  uint y = (chunk >> 10) & 255u;
  uint b = chunk >> 18;
  const float* src = in + (((size_t)b * 32 + g * 8) * 256 + y) * 256 + x;
  uint w0 = (uint)f2bf(src[0])         | ((uint)f2bf(src[1 * 65536]) << 16);
  uint w1 = (uint)f2bf(src[2 * 65536]) | ((uint)f2bf(src[3 * 65536]) << 16);
  uint w2 = (uint)f2bf(src[4 * 65536]) | ((uint)f2bf(src[5 * 65536]) << 16);
  uint w3 = (uint)f2bf(src[6 * 65536]) | ((uint)f2bf(src[7 * 65536]) << 16);
  *(uint4*)(out + (size_t)chunk * 8) = make_uint4(w0, w1, w2, w3);
}

// ---------------- pre-pass 2: weights -> bf16, layout wt[h][kx][ky(32, pad0)][frag] ----
// flat ushort idx = (((h*31+kx)*32 + ky)*64 + j)*8 + i ; j: col=j&31 (cout), g=j>>5
// element i: c = h*16 + g*8 + i ; ky==31 is a zero pad line.
extern "C" __global__ void cvt_wt(const float* __restrict__ w, ushort* __restrict__ wt) {
  uint tid = blockIdx.x * 256 + threadIdx.x;       // 2*31*32*512 = 1015808 total
  uint i = tid & 7u;
  uint j = (tid >> 3) & 63u;
  uint rest = tid >> 9;                            // < 1984
  uint ky = rest & 31u;
  uint kxh = rest >> 5;                            // < 62
  uint kx = kxh % 31u;
  uint h  = kxh / 31u;
  uint col = j & 31u;
  uint g   = j >> 5;
  uint c = h * 16u + g * 8u + i;
  float v = 0.0f;
  if (ky < 31u) v = w[((col * 32u + c) * 31u + ky) * 31u + kx];
  wt[tid] = f2bf(v);
}

// ---------------- main conv: 32x32 tile, 8 waves, kx-outer / ky-inner ----------------
// A ring depth 4 (as r5, the 58%-util structure); B ring depth 4 (NEW: was 2).
// Phase kk: 4 MFMAs rows kk..kk+3 x B line kk; then load B line kk+4 (slot kk%4)
// and A row kk+4 (slot kk%4). B consumed 4 phases (~16 MFMA) later.
#define PH(qa, qb, qc, qd, bReg, kk)                                              \
  acc0 = MFMA32(qa, bReg, acc0);                                                  \
  acc1 = MFMA32(qb, bReg, acc1);                                                  \
  acc2 = MFMA32(qc, bReg, acc2);                                                  \
  acc3 = MFMA32(qd, bReg, acc3);                                                  \
  if ((kk) + 4 < 32) bReg = *(const bf16x8*)(wb + ((kk) + 4) * 1024 + lane * 16); \
  qa = *(const bf16x8*)(ab + ((kk) + 4) * ROWB);

#define GROUP4(k0)                    \
  PH(r0, r1, r2, r3, bA, (k0) + 0)    \
  PH(r1, r2, r3, r0, bB, (k0) + 1)    \
  PH(r2, r3, r0, r1, bC, (k0) + 2)    \
  PH(r3, r0, r1, r2, bD, (k0) + 3)

extern "C" __global__ void __launch_bounds__(512, 2)
conv_main(const ushort* __restrict__ sigbf, const char* __restrict__ wtbf,
          const float* __restrict__ bias, float* __restrict__ out) {
  extern __shared__ char lds[];
  const int tid = threadIdx.x;
  const int lane = tid & 63;
  const int wv  = tid >> 6;        // 0..7, owns output rows wv*4 .. wv*4+3
  const int l31 = lane & 31;       // = M row (ox offset) for A, = cout col for B/C
  const int hi  = lane >> 5;       // k-half selector of the fragment
  const int ox0 = blockIdx.x * 32, oy0 = blockIdx.y * 32;
  const int bb = blockIdx.z;

  f32x16 acc0, acc1, acc2, acc3;
#pragma unroll
  for (int i = 0; i < 16; ++i) { acc0[i] = 0.f; acc1[i] = 0.f; acc2[i] = 0.f; acc3[i] = 0.f; }

  for (int h = 0; h < 2; ++h) {     // two 16-channel halves; acc persists
    if (h) __syncthreads();         // previous half's compute done before overwrite
    // ---- stage input tile half: 63*62 pixels * 16ch bf16, XOR-swizzled 16B chunks ----
#pragma unroll
    for (int it = 0; it < 16; ++it) {
      int c = it * 512 + tid;
      if (c < 63 * 62 * 2) {
        int p = c >> 1, sub = c & 1;
        int ty = p / ITX;
        int tx = p - ty * ITX;
        int gy = oy0 + ty; gy = gy > 255 ? 255 : gy;   // clamp: only feeds discarded outputs
        int gx = ox0 + tx; gx = gx > 255 ? 255 : gx;
        uint4 v = *(const uint4*)(sigbf +
            ((((size_t)bb << 8) + gy) * 256 + gx) * 32 + h * 16 + sub * 8);
        uint off = (uint)(ty * ROWB + tx * 32 + sub * 16);
        off ^= (((uint)(tx >> 2)) & 1u) << 4;          // bank-spread swizzle (16B slot)
        *(uint4*)(lds + off) = v;
      }
    }
    __syncthreads();

    const char* wcol = wtbf + (((size_t)h * 31) << 15);
#pragma unroll 1
    for (int kx = 0; kx < 31; ++kx) {
      const char* wb = wcol + ((size_t)kx << 15);      // 32KB contiguous ky-column
      int col = l31 + kx;                              // 0..61
      uint apix = ((uint)col * 32u + (uint)hi * 16u) ^ (((uint)(col >> 2) & 1u) << 4);
      const char* ab = lds + (uint)(wv * 4) * ROWB + apix;
      // A ring init: rows wv*4 + 0..3 (slot = relative row mod 4)
      bf16x8 r0 = *(const bf16x8*)(ab + 0 * ROWB);
      bf16x8 r1 = *(const bf16x8*)(ab + 1 * ROWB);
      bf16x8 r2 = *(const bf16x8*)(ab + 2 * ROWB);
      bf16x8 r3 = *(const bf16x8*)(ab + 3 * ROWB);
      // B ring init: lines 0..3 (slot = line mod 4)
      bf16x8 bA = *(const bf16x8*)(wb + 0 * 1024 + lane * 16);
      bf16x8 bB = *(const bf16x8*)(wb + 1 * 1024 + lane * 16);
      bf16x8 bC = *(const bf16x8*)(wb + 2 * 1024 + lane * 16);
      bf16x8 bD = *(const bf16x8*)(wb + 3 * 1024 + lane * 16);
      GROUP4(0)
      GROUP4(4)
      GROUP4(8)
      GROUP4(12)
      GROUP4(16)
      GROUP4(20)
      GROUP4(24)
      GROUP4(28)    // taps 28..31; tap 31 is the zero pad line
    }
  }

  // ---- epilogue: C/D layout col=lane&31 (=cout), row=(r&3)+8*(r>>2)+4*hi (=ox) ----
  float bv = bias[l31];
  f32x16 accv[4] = {acc0, acc1, acc2, acc3};
#pragma unroll
  for (int t = 0; t < 4; ++t) {
    int oy = oy0 + wv * 4 + t;
    if (oy >= 226) continue;
    size_t ob = (((size_t)bb * 32 + l31) * 226 + oy) * 226;
#pragma unroll
    for (int q = 0; q < 4; ++q) {
      int ox = ox0 + q * 8 + hi * 4;
      float4 v = make_float4(accv[t][4 * q + 0] + bv, accv[t][4 * q + 1] + bv,
                             accv[t][4 * q + 2] + bv, accv[t][4 * q + 3] + bv);
      if (ox + 3 < 226) {
        *(float4*)(out + ob + ox) = v;
      } else {
        if (ox + 0 < 226) out[ob + ox + 0] = v.x;
        if (ox + 1 < 226) out[ob + ox + 1] = v.y;
        if (ox + 2 < 226) out[ob + ox + 2] = v.z;
        if (ox + 3 < 226) out[ob + ox + 3] = v.w;
      }
    }
  }
}

extern "C" void kernel_launch(void* const* d_in, const int* in_sizes, int n_in,
                              void* d_out, int out_size, void* d_ws, size_t ws_size,
                              hipStream_t stream) {
  const float* sig = (const float*)d_in[0];
  const float* wgt = (const float*)d_in[1];
  const float* bia = (const float*)d_in[2];
  float* out = (float*)d_out;
  ushort* sigbf = (ushort*)d_ws;                       // 16*256*256*32 bf16 = 64 MiB
  char*   wtbf  = (char*)d_ws + 67108864;              // 2*31*32KB = 1.94 MiB

  (void)hipFuncSetAttribute(reinterpret_cast<const void*>(conv_main),
                            hipFuncAttributeMaxDynamicSharedMemorySize, LDS_BYTES);

  cvt_sig<<<16384, 256, 0, stream>>>(sig, sigbf);
  cvt_wt<<<3968, 256, 0, stream>>>(wgt, (ushort*)wtbf);
  conv_main<<<dim3(8, 8, 16), 512, LDS_BYTES, stream>>>(sigbf, wtbf, bia, out);

  (void)in_sizes; (void)n_in; (void)out_size; (void)ws_size;
}